// Round 1
// baseline (1677.849 us; speedup 1.0000x reference)
//
#include <hip/hip_runtime.h>

#define DIMC   3072
#define HEADS  24
#define HD     128
#define FF     12288
#define S_IMG  1024
#define S_TXT  256
#define S_TOT  1280
#define EPSF   1e-6f

typedef __attribute__((ext_vector_type(8))) short bf16x8;
typedef __attribute__((ext_vector_type(4))) float f32x4;
typedef __attribute__((ext_vector_type(4))) float float4v;

__device__ __forceinline__ unsigned short f2bf(float f) {
    union { float f; unsigned u; } c; c.f = f;
    unsigned u = c.u;
    unsigned r = (u + 0x7fffu + ((u >> 16) & 1u)) >> 16;  // RTNE
    return (unsigned short)r;
}
__device__ __forceinline__ float b2f(unsigned short h) {
    union { unsigned u; float f; } c; c.u = ((unsigned)h) << 16;
    return c.f;
}

// ---------------------------------------------------------------------------
// Generic C = A(MxK,bf16) * B(NxK)^T + bias, 128x128 tile, BK=64, 4 waves.
// B is fp32 (converted on the fly) or bf16. XOR-swizzled LDS (T2).
// EPI: 0 = fp32 store; 1 = bf16 store; 2 = gelu(tanh)->bf16; 3 = base + gate*v -> fp32
// ---------------------------------------------------------------------------
template<int EPI, bool BF16B>
__global__ __launch_bounds__(256)
void gemm_bt(const unsigned short* __restrict__ A, const void* __restrict__ Bp,
             const float* __restrict__ bias, void* __restrict__ out,
             const float* __restrict__ base, const float* __restrict__ gate,
             int K, int lda, int ldb, int ldout,
             long batchA, long batchB, long batchOut)
{
    __shared__ __align__(16) unsigned short As[128 * 64];
    __shared__ __align__(16) unsigned short Bs[128 * 64];

    const int tid  = threadIdx.x;
    const int lane = tid & 63;
    const int wave = tid >> 6;
    const int wm = wave >> 1, wc = wave & 1;
    const int bm = blockIdx.y * 128, bn = blockIdx.x * 128;

    A += (long)blockIdx.z * batchA;
    const float* Bf = (const float*)Bp;
    const unsigned short* Bh = (const unsigned short*)Bp;
    const long boff = (long)blockIdx.z * batchB;

    const int kc = tid & 7;          // 16B chunk within a 64-elem row
    const int rbase = tid >> 3;      // 0..31

    f32x4 acc[4][4] = {};

    for (int k0 = 0; k0 < K; k0 += 64) {
        // stage A (bf16 -> LDS, swizzled)
        #pragma unroll
        for (int i = 0; i < 4; i++) {
            int r = i * 32 + rbase;
            bf16x8 v = *(const bf16x8*)(A + (long)(bm + r) * lda + k0 + kc * 8);
            *(bf16x8*)((char*)As + r * 128 + ((kc * 16) ^ ((r & 7) << 4))) = v;
        }
        // stage B (fp32->bf16 cvt or bf16 direct)
        #pragma unroll
        for (int i = 0; i < 4; i++) {
            int r = i * 32 + rbase;
            bf16x8 v;
            if constexpr (BF16B) {
                v = *(const bf16x8*)(Bh + boff + (long)(bn + r) * ldb + k0 + kc * 8);
            } else {
                const float* src = Bf + boff + (long)(bn + r) * ldb + k0 + kc * 8;
                float4v f0 = *(const float4v*)src;
                float4v f1 = *(const float4v*)(src + 4);
                bf16x8 t;
                t[0] = (short)f2bf(f0[0]); t[1] = (short)f2bf(f0[1]);
                t[2] = (short)f2bf(f0[2]); t[3] = (short)f2bf(f0[3]);
                t[4] = (short)f2bf(f1[0]); t[5] = (short)f2bf(f1[1]);
                t[6] = (short)f2bf(f1[2]); t[7] = (short)f2bf(f1[3]);
                v = t;
            }
            *(bf16x8*)((char*)Bs + r * 128 + ((kc * 16) ^ ((r & 7) << 4))) = v;
        }
        __syncthreads();

        #pragma unroll
        for (int ks = 0; ks < 2; ks++) {
            const int kb = ks * 64 + (lane >> 4) * 16;   // byte offset along k
            bf16x8 af[4], bfr[4];
            #pragma unroll
            for (int mi = 0; mi < 4; mi++) {
                int r = wm * 64 + mi * 16 + (lane & 15);
                af[mi] = *(const bf16x8*)((const char*)As + r * 128 + (kb ^ ((r & 7) << 4)));
            }
            #pragma unroll
            for (int ni = 0; ni < 4; ni++) {
                int r = wc * 64 + ni * 16 + (lane & 15);
                bfr[ni] = *(const bf16x8*)((const char*)Bs + r * 128 + (kb ^ ((r & 7) << 4)));
            }
            #pragma unroll
            for (int mi = 0; mi < 4; mi++)
                #pragma unroll
                for (int ni = 0; ni < 4; ni++)
                    acc[mi][ni] = __builtin_amdgcn_mfma_f32_16x16x32_bf16(
                        af[mi], bfr[ni], acc[mi][ni], 0, 0, 0);
        }
        __syncthreads();
    }

    unsigned short* outh = (unsigned short*)out + (long)blockIdx.z * batchOut;
    float*          outf = (float*)out + (long)blockIdx.z * batchOut;
    #pragma unroll
    for (int mi = 0; mi < 4; mi++) {
        #pragma unroll
        for (int ni = 0; ni < 4; ni++) {
            int n = bn + wc * 64 + ni * 16 + (lane & 15);
            float bv = bias ? bias[n] : 0.0f;
            #pragma unroll
            for (int r = 0; r < 4; r++) {
                int m = bm + wm * 64 + mi * 16 + (lane >> 4) * 4 + r;
                float v = acc[mi][ni][r] + bv;
                long o = (long)m * ldout + n;
                if constexpr (EPI == 0) {
                    outf[o] = v;
                } else if constexpr (EPI == 1) {
                    outh[o] = f2bf(v);
                } else if constexpr (EPI == 2) {
                    float t = tanhf(0.7978845608028654f * (v + 0.044715f * v * v * v));
                    outh[o] = f2bf(0.5f * v * (1.0f + t));
                } else {
                    outf[o] = base[o] + gate[n] * v;
                }
            }
        }
    }
}

// ---------------------------------------------------------------------------
// silu(temb)
// ---------------------------------------------------------------------------
__global__ void silu_k(const float* __restrict__ x, float* __restrict__ out) {
    int i = blockIdx.x * 256 + threadIdx.x;
    if (i < DIMC) { float v = x[i]; out[i] = v / (1.0f + expf(-v)); }
}

// ---------------------------------------------------------------------------
// mod GEMV: out[j*DIM + d] = dot(silu_temb, W[r]) + b[r], r = d*6+j
// one wave per row; grid.y selects img/txt
// ---------------------------------------------------------------------------
__global__ __launch_bounds__(256)
void mod_gemv(const float* __restrict__ st,
              const float* __restrict__ Wimg, const float* __restrict__ bimg,
              const float* __restrict__ Wtxt, const float* __restrict__ btxt,
              float* __restrict__ mimg, float* __restrict__ mtxt)
{
    int wv = threadIdx.x >> 6, lane = threadIdx.x & 63;
    int r = blockIdx.x * 4 + wv;                 // 0..18431
    const float* W = blockIdx.y ? Wtxt : Wimg;
    const float* b = blockIdx.y ? btxt : bimg;
    float* out = blockIdx.y ? mtxt : mimg;
    const float* row = W + (long)r * DIMC;
    float acc = 0.f;
    #pragma unroll
    for (int j = 0; j < 12; j++) {
        float4v wvv = ((const float4v*)row)[lane + j * 64];
        float4v xv  = ((const float4v*)st)[lane + j * 64];
        acc += wvv[0] * xv[0] + wvv[1] * xv[1] + wvv[2] * xv[2] + wvv[3] * xv[3];
    }
    #pragma unroll
    for (int o = 32; o; o >>= 1) acc += __shfl_xor(acc, o);
    if (lane == 0) {
        int d = r / 6, j6 = r % 6;
        out[j6 * DIMC + d] = acc + b[r];
    }
}

// ---------------------------------------------------------------------------
// LayerNorm + modulate -> bf16 : out = ln(x)*(scale+1)+shift. One block/row.
// ---------------------------------------------------------------------------
__global__ __launch_bounds__(256)
void ln_mod(const float* __restrict__ x, const float* __restrict__ shift,
            const float* __restrict__ scale, unsigned short* __restrict__ out)
{
    __shared__ float red[8];
    long row = blockIdx.x;
    const float* xr = x + row * DIMC;
    float4v v[3];
    float sum = 0.f, sq = 0.f;
    #pragma unroll
    for (int j = 0; j < 3; j++) {
        v[j] = ((const float4v*)xr)[threadIdx.x + j * 256];
        #pragma unroll
        for (int c = 0; c < 4; c++) { sum += v[j][c]; sq += v[j][c] * v[j][c]; }
    }
    int lane = threadIdx.x & 63, wv = threadIdx.x >> 6;
    #pragma unroll
    for (int o = 32; o; o >>= 1) { sum += __shfl_xor(sum, o); sq += __shfl_xor(sq, o); }
    if (lane == 0) { red[wv] = sum; red[4 + wv] = sq; }
    __syncthreads();
    sum = red[0] + red[1] + red[2] + red[3];
    sq  = red[4] + red[5] + red[6] + red[7];
    float mu = sum / DIMC;
    float var = sq / DIMC - mu * mu;
    float rstd = rsqrtf(var + EPSF);
    #pragma unroll
    for (int j = 0; j < 3; j++) {
        int nb = (threadIdx.x + j * 256) * 4;
        #pragma unroll
        for (int c = 0; c < 4; c++) {
            int n = nb + c;
            float y = (v[j][c] - mu) * rstd * (scale[n] + 1.0f) + shift[n];
            out[row * DIMC + n] = f2bf(y);
        }
    }
}

// ---------------------------------------------------------------------------
// QKV post: RMS-norm(q,k) + RoPE + scale q; emit q,k [h][s][d] bf16, v^T [h][d][s]
// block: 64 threads (1 wave) handles one (s,h); thread owns d and d+64.
// ---------------------------------------------------------------------------
__global__ __launch_bounds__(64)
void qkv_post(const float* __restrict__ qkv_img, const float* __restrict__ qkv_txt,
              const float* __restrict__ nqg, const float* __restrict__ nkg,
              const float* __restrict__ naqg, const float* __restrict__ nakg,
              const float* __restrict__ rc, const float* __restrict__ rs,
              unsigned short* __restrict__ q, unsigned short* __restrict__ k,
              unsigned short* __restrict__ vt)
{
    int s = blockIdx.x;   // 0..1279 (txt first)
    int h = blockIdx.y;
    int d0 = threadIdx.x; // 0..63
    const float *src, *gq, *gk;
    if (s < S_TXT) { src = qkv_txt + (long)s * 3 * DIMC; gq = naqg; gk = nakg; }
    else           { src = qkv_img + (long)(s - S_TXT) * 3 * DIMC; gq = nqg; gk = nkg; }

    float q0 = src[h * HD + d0],            q1 = src[h * HD + d0 + 64];
    float k0 = src[DIMC + h * HD + d0],     k1 = src[DIMC + h * HD + d0 + 64];
    float v0 = src[2 * DIMC + h * HD + d0], v1 = src[2 * DIMC + h * HD + d0 + 64];

    float sqq = q0 * q0 + q1 * q1;
    float sqk = k0 * k0 + k1 * k1;
    #pragma unroll
    for (int o = 32; o; o >>= 1) { sqq += __shfl_xor(sqq, o); sqk += __shfl_xor(sqk, o); }
    float rq = rsqrtf(sqq / (float)HD + EPSF);
    float rk = rsqrtf(sqk / (float)HD + EPSF);
    q0 *= rq * gq[d0]; q1 *= rq * gq[d0 + 64];
    k0 *= rk * gk[d0]; k1 *= rk * gk[d0 + 64];

    float qp0 = __shfl_xor(q0, 1), qp1 = __shfl_xor(q1, 1);
    float kp0 = __shfl_xor(k0, 1), kp1 = __shfl_xor(k1, 1);
    float c0 = rc[(long)s * HD + d0], c1 = rc[(long)s * HD + d0 + 64];
    float s0 = rs[(long)s * HD + d0], s1 = rs[(long)s * HD + d0 + 64];
    float sgn = (d0 & 1) ? 1.0f : -1.0f;
    float qo0 = q0 * c0 + sgn * qp0 * s0;
    float qo1 = q1 * c1 + sgn * qp1 * s1;
    float ko0 = k0 * c0 + sgn * kp0 * s0;
    float ko1 = k1 * c1 + sgn * kp1 * s1;

    const float scl = 0.08838834764831845f;   // 1/sqrt(128)
    long qkbase = ((long)h * S_TOT + s) * HD;
    q[qkbase + d0]      = f2bf(qo0 * scl);
    q[qkbase + d0 + 64] = f2bf(qo1 * scl);
    k[qkbase + d0]      = f2bf(ko0);
    k[qkbase + d0 + 64] = f2bf(ko1);
    vt[((long)h * HD + d0) * S_TOT + s]        = f2bf(v0);
    vt[((long)h * HD + d0 + 64) * S_TOT + s]   = f2bf(v1);
}

// ---------------------------------------------------------------------------
// softmax in-place over rows of 1280 (bf16). one wave per row, 4 rows/block.
// ---------------------------------------------------------------------------
__global__ __launch_bounds__(256)
void softmax_k(unsigned short* __restrict__ scores)
{
    long row = (long)blockIdx.x * 4 + (threadIdx.x >> 6);
    int lane = threadIdx.x & 63;
    unsigned short* p = scores + row * S_TOT;
    float v[20];
    float mx = -1e30f;
    #pragma unroll
    for (int j = 0; j < 20; j++) { v[j] = b2f(p[lane + j * 64]); mx = fmaxf(mx, v[j]); }
    #pragma unroll
    for (int o = 32; o; o >>= 1) mx = fmaxf(mx, __shfl_xor(mx, o));
    float sum = 0.f;
    #pragma unroll
    for (int j = 0; j < 20; j++) { v[j] = expf(v[j] - mx); sum += v[j]; }
    #pragma unroll
    for (int o = 32; o; o >>= 1) sum += __shfl_xor(sum, o);
    float inv = 1.0f / sum;
    #pragma unroll
    for (int j = 0; j < 20; j++) p[lane + j * 64] = f2bf(v[j] * inv);
}

// ---------------------------------------------------------------------------
extern "C" void kernel_launch(void* const* d_in, const int* in_sizes, int n_in,
                              void* d_out, int out_size, void* d_ws, size_t ws_size,
                              hipStream_t stream)
{
    const float* hidden   = (const float*)d_in[0];
    const float* enc      = (const float*)d_in[1];
    const float* temb     = (const float*)d_in[2];
    const float* rope_cos = (const float*)d_in[3];
    const float* rope_sin = (const float*)d_in[4];
    const float* img_mod_w = (const float*)d_in[5];
    const float* img_mod_b = (const float*)d_in[6];
    const float* txt_mod_w = (const float*)d_in[7];
    const float* txt_mod_b = (const float*)d_in[8];
    const float* qkv_w     = (const float*)d_in[9];
    const float* qkv_b     = (const float*)d_in[10];
    const float* add_qkv_w = (const float*)d_in[11];
    const float* add_qkv_b = (const float*)d_in[12];
    const float* norm_q_g  = (const float*)d_in[13];
    const float* norm_k_g  = (const float*)d_in[14];
    const float* norm_aq_g = (const float*)d_in[15];
    const float* norm_ak_g = (const float*)d_in[16];
    const float* to_out_w  = (const float*)d_in[17];
    const float* to_out_b  = (const float*)d_in[18];
    const float* to_add_out_w = (const float*)d_in[19];
    const float* to_add_out_b = (const float*)d_in[20];
    const float* img_mlp_w1 = (const float*)d_in[21];
    const float* img_mlp_b1 = (const float*)d_in[22];
    const float* img_mlp_w2 = (const float*)d_in[23];
    const float* img_mlp_b2 = (const float*)d_in[24];
    const float* txt_mlp_w1 = (const float*)d_in[25];
    const float* txt_mlp_b1 = (const float*)d_in[26];
    const float* txt_mlp_w2 = (const float*)d_in[27];
    const float* txt_mlp_b2 = (const float*)d_in[28];

    char* w = (char*)d_ws;
    auto alloc = [&](size_t bytes) { char* p = w; w += (bytes + 255) & ~(size_t)255; return p; };
    float* silu_t  = (float*)alloc(DIMC * 4);
    float* mod_img = (float*)alloc(6 * DIMC * 4);
    float* mod_txt = (float*)alloc(6 * DIMC * 4);
    unsigned short* mA_img = (unsigned short*)alloc((long)S_IMG * DIMC * 2);
    unsigned short* mA_txt = (unsigned short*)alloc((long)S_TXT * DIMC * 2);
    float* qkv_img = (float*)alloc((long)S_IMG * 3 * DIMC * 4);
    float* qkv_txt = (float*)alloc((long)S_TXT * 3 * DIMC * 4);
    unsigned short* qb = (unsigned short*)alloc((long)HEADS * S_TOT * HD * 2);
    unsigned short* kb = (unsigned short*)alloc((long)HEADS * S_TOT * HD * 2);
    unsigned short* vt = (unsigned short*)alloc((long)HEADS * HD * S_TOT * 2);
    unsigned short* scores = (unsigned short*)alloc((long)HEADS * S_TOT * S_TOT * 2);
    unsigned short* attn = (unsigned short*)alloc((long)S_TOT * DIMC * 2);
    float* h1_img = (float*)alloc((long)S_IMG * DIMC * 4);
    float* h1_txt = (float*)alloc((long)S_TXT * DIMC * 4);
    unsigned short* gelu_img = (unsigned short*)alloc((long)S_IMG * FF * 2);
    unsigned short* gelu_txt = (unsigned short*)alloc((long)S_TXT * FF * 2);

    float* out_enc = (float*)d_out;
    float* out_hid = (float*)d_out + (long)S_TXT * DIMC;

    // 1. silu(temb), mod GEMVs
    silu_k<<<12, 256, 0, stream>>>(temb, silu_t);
    mod_gemv<<<dim3(4608, 2), 256, 0, stream>>>(silu_t, img_mod_w, img_mod_b,
                                                txt_mod_w, txt_mod_b, mod_img, mod_txt);

    // 2. LN1 + modulate -> bf16
    ln_mod<<<S_IMG, 256, 0, stream>>>(hidden, mod_img, mod_img + DIMC, mA_img);
    ln_mod<<<S_TXT, 256, 0, stream>>>(enc, mod_txt, mod_txt + DIMC, mA_txt);

    // 3. QKV GEMMs (fp32 out, bias fused)
    gemm_bt<0, false><<<dim3(72, 8, 1), 256, 0, stream>>>(
        mA_img, qkv_w, qkv_b, qkv_img, nullptr, nullptr,
        DIMC, DIMC, DIMC, 3 * DIMC, 0, 0, 0);
    gemm_bt<0, false><<<dim3(72, 2, 1), 256, 0, stream>>>(
        mA_txt, add_qkv_w, add_qkv_b, qkv_txt, nullptr, nullptr,
        DIMC, DIMC, DIMC, 3 * DIMC, 0, 0, 0);

    // 4. RMS + RoPE + layout
    qkv_post<<<dim3(S_TOT, HEADS), 64, 0, stream>>>(
        qkv_img, qkv_txt, norm_q_g, norm_k_g, norm_aq_g, norm_ak_g,
        rope_cos, rope_sin, qb, kb, vt);

    // 5. scores = q k^T (scale folded in q), softmax, attn = P v
    gemm_bt<1, true><<<dim3(10, 10, HEADS), 256, 0, stream>>>(
        qb, kb, nullptr, scores, nullptr, nullptr,
        HD, HD, HD, S_TOT, (long)S_TOT * HD, (long)S_TOT * HD, (long)S_TOT * S_TOT);
    softmax_k<<<(HEADS * S_TOT) / 4, 256, 0, stream>>>(scores);
    gemm_bt<1, true><<<dim3(1, 10, HEADS), 256, 0, stream>>>(
        scores, vt, nullptr, attn, nullptr, nullptr,
        S_TOT, S_TOT, S_TOT, DIMC, (long)S_TOT * S_TOT, (long)HD * S_TOT, HD);

    // 6. output projections + gated residual
    gemm_bt<3, false><<<dim3(24, 8, 1), 256, 0, stream>>>(
        attn + (long)S_TXT * DIMC, to_out_w, to_out_b, h1_img, hidden, mod_img + 2 * DIMC,
        DIMC, DIMC, DIMC, DIMC, 0, 0, 0);
    gemm_bt<3, false><<<dim3(24, 2, 1), 256, 0, stream>>>(
        attn, to_add_out_w, to_add_out_b, h1_txt, enc, mod_txt + 2 * DIMC,
        DIMC, DIMC, DIMC, DIMC, 0, 0, 0);

    // 7. LN2 + modulate
    ln_mod<<<S_IMG, 256, 0, stream>>>(h1_img, mod_img + 3 * DIMC, mod_img + 4 * DIMC, mA_img);
    ln_mod<<<S_TXT, 256, 0, stream>>>(h1_txt, mod_txt + 3 * DIMC, mod_txt + 4 * DIMC, mA_txt);

    // 8. MLP: w1+gelu -> bf16, then w2 + gated residual -> d_out
    gemm_bt<2, false><<<dim3(96, 8, 1), 256, 0, stream>>>(
        mA_img, img_mlp_w1, img_mlp_b1, gelu_img, nullptr, nullptr,
        DIMC, DIMC, DIMC, FF, 0, 0, 0);
    gemm_bt<2, false><<<dim3(96, 2, 1), 256, 0, stream>>>(
        mA_txt, txt_mlp_w1, txt_mlp_b1, gelu_txt, nullptr, nullptr,
        DIMC, DIMC, DIMC, FF, 0, 0, 0);

    gemm_bt<3, false><<<dim3(24, 8, 1), 256, 0, stream>>>(
        gelu_img, img_mlp_w2, img_mlp_b2, out_hid, h1_img, mod_img + 5 * DIMC,
        FF, FF, FF, DIMC, 0, 0, 0);
    gemm_bt<3, false><<<dim3(24, 2, 1), 256, 0, stream>>>(
        gelu_txt, txt_mlp_w2, txt_mlp_b2, out_enc, h1_txt, mod_txt + 5 * DIMC,
        FF, FF, FF, DIMC, 0, 0, 0);
}

// Round 2
// 927.218 us; speedup vs baseline: 1.8096x; 1.8096x over previous
//
#include <hip/hip_runtime.h>

#define DIMC   3072
#define HEADS  24
#define HD     128
#define FF     12288
#define S_IMG  1024
#define S_TXT  256
#define S_TOT  1280
#define EPSF   1e-6f

typedef __attribute__((ext_vector_type(8))) short bf16x8;
typedef __attribute__((ext_vector_type(4))) float f32x4;
typedef __attribute__((ext_vector_type(4))) float float4v;

__device__ __forceinline__ unsigned short f2bf(float f) {
    union { float f; unsigned u; } c; c.f = f;
    unsigned u = c.u;
    unsigned r = (u + 0x7fffu + ((u >> 16) & 1u)) >> 16;  // RTNE
    return (unsigned short)r;
}
__device__ __forceinline__ float b2f(unsigned short h) {
    union { unsigned u; float f; } c; c.u = ((unsigned)h) << 16;
    return c.f;
}

struct GemmArgs {
    const unsigned short* A;
    const void* B;
    const float* bias;
    void* out;
    const float* base;
    const float* gate;
};

// ---------------------------------------------------------------------------
// C = A(MxK,bf16) * B(NxK)^T + bias. 128x128 tile, BK=64, 4 waves.
// Reg-staged double-buffered pipeline (issue-early / write-late).
// Two arg-sets: blockIdx.y < ysplit -> g0 (row by), else g1 (row by-ysplit).
// EPI: 0 fp32 store; 1 bf16 store; 2 gelu(tanh)->bf16; 3 base + gate*v -> fp32
// ---------------------------------------------------------------------------
template<int EPI, bool BF16B>
__global__ __launch_bounds__(256)
void gemm_bt(GemmArgs g0, GemmArgs g1, int ysplit,
             int K, int lda, int ldb, int ldout,
             long batchA, long batchB, long batchOut)
{
    __shared__ __align__(16) unsigned short As[2][128 * 64];
    __shared__ __align__(16) unsigned short Bs[2][128 * 64];

    const int tid  = threadIdx.x;
    const int lane = tid & 63;
    const int wave = tid >> 6;
    const int wm = wave >> 1, wc = wave & 1;

    const int by = blockIdx.y;
    const bool second = (by >= ysplit);
    const GemmArgs g = second ? g1 : g0;
    const int bm = (second ? by - ysplit : by) * 128;
    const int bn = blockIdx.x * 128;

    const unsigned short* A = g.A + (long)blockIdx.z * batchA;
    const float* Bf = (const float*)g.B + (long)blockIdx.z * batchB;
    const unsigned short* Bh = (const unsigned short*)g.B + (long)blockIdx.z * batchB;

    const int kc = tid & 7;          // 16B chunk within a 64-elem row
    const int rbase = tid >> 3;      // 0..31

    f32x4 acc[4][4] = {};

    bf16x8  ra[4];
    bf16x8  rbh[4];
    float4v rb0[4], rb1[4];

    auto LOAD = [&](int t) {
        long kof = (long)t * 64 + kc * 8;
        #pragma unroll
        for (int i = 0; i < 4; i++) {
            int r = i * 32 + rbase;
            ra[i] = *(const bf16x8*)(A + (long)(bm + r) * lda + kof);
            if constexpr (BF16B) {
                rbh[i] = *(const bf16x8*)(Bh + (long)(bn + r) * ldb + kof);
            } else {
                const float* src = Bf + (long)(bn + r) * ldb + kof;
                rb0[i] = *(const float4v*)src;
                rb1[i] = *(const float4v*)(src + 4);
            }
        }
    };

    auto STORE = [&](int buf) {
        #pragma unroll
        for (int i = 0; i < 4; i++) {
            int r = i * 32 + rbase;
            int off = r * 128 + ((kc * 16) ^ ((r & 7) << 4));
            *(bf16x8*)((char*)As[buf] + off) = ra[i];
            bf16x8 v;
            if constexpr (BF16B) {
                v = rbh[i];
            } else {
                v[0] = (short)f2bf(rb0[i][0]); v[1] = (short)f2bf(rb0[i][1]);
                v[2] = (short)f2bf(rb0[i][2]); v[3] = (short)f2bf(rb0[i][3]);
                v[4] = (short)f2bf(rb1[i][0]); v[5] = (short)f2bf(rb1[i][1]);
                v[6] = (short)f2bf(rb1[i][2]); v[7] = (short)f2bf(rb1[i][3]);
            }
            *(bf16x8*)((char*)Bs[buf] + off) = v;
        }
    };

    auto COMPUTE = [&](int buf) {
        #pragma unroll
        for (int ks = 0; ks < 2; ks++) {
            const int kb = ks * 64 + (lane >> 4) * 16;   // byte offset along k
            bf16x8 af[4], bfr[4];
            #pragma unroll
            for (int mi = 0; mi < 4; mi++) {
                int r = wm * 64 + mi * 16 + (lane & 15);
                af[mi] = *(const bf16x8*)((const char*)As[buf] + r * 128 + (kb ^ ((r & 7) << 4)));
            }
            #pragma unroll
            for (int ni = 0; ni < 4; ni++) {
                int r = wc * 64 + ni * 16 + (lane & 15);
                bfr[ni] = *(const bf16x8*)((const char*)Bs[buf] + r * 128 + (kb ^ ((r & 7) << 4)));
            }
            #pragma unroll
            for (int mi = 0; mi < 4; mi++)
                #pragma unroll
                for (int ni = 0; ni < 4; ni++)
                    acc[mi][ni] = __builtin_amdgcn_mfma_f32_16x16x32_bf16(
                        af[mi], bfr[ni], acc[mi][ni], 0, 0, 0);
        }
    };

    const int nk = K >> 6;
    LOAD(0);
    STORE(0);
    __syncthreads();
    for (int t = 0; t < nk; ++t) {
        const int cur = t & 1;
        if (t + 1 < nk) LOAD(t + 1);       // issue next-tile global loads early
        COMPUTE(cur);                      // ds_read + MFMA hide the HBM latency
        if (t + 1 < nk) STORE(cur ^ 1);    // vmcnt-wait + cvt + ds_write late
        __syncthreads();
    }

    unsigned short* outh = (unsigned short*)g.out + (long)blockIdx.z * batchOut;
    float*          outf = (float*)g.out + (long)blockIdx.z * batchOut;
    #pragma unroll
    for (int mi = 0; mi < 4; mi++) {
        #pragma unroll
        for (int ni = 0; ni < 4; ni++) {
            int n = bn + wc * 64 + ni * 16 + (lane & 15);
            float bv = g.bias ? g.bias[n] : 0.0f;
            #pragma unroll
            for (int r = 0; r < 4; r++) {
                int m = bm + wm * 64 + mi * 16 + (lane >> 4) * 4 + r;
                float v = acc[mi][ni][r] + bv;
                long o = (long)m * ldout + n;
                if constexpr (EPI == 0) {
                    outf[o] = v;
                } else if constexpr (EPI == 1) {
                    outh[o] = f2bf(v);
                } else if constexpr (EPI == 2) {
                    float t = tanhf(0.7978845608028654f * (v + 0.044715f * v * v * v));
                    outh[o] = f2bf(0.5f * v * (1.0f + t));
                } else {
                    outf[o] = g.base[o] + g.gate[n] * v;
                }
            }
        }
    }
}

// ---------------------------------------------------------------------------
__global__ void silu_k(const float* __restrict__ x, float* __restrict__ out) {
    int i = blockIdx.x * 256 + threadIdx.x;
    if (i < DIMC) { float v = x[i]; out[i] = v / (1.0f + expf(-v)); }
}

// ---------------------------------------------------------------------------
__global__ __launch_bounds__(256)
void mod_gemv(const float* __restrict__ st,
              const float* __restrict__ Wimg, const float* __restrict__ bimg,
              const float* __restrict__ Wtxt, const float* __restrict__ btxt,
              float* __restrict__ mimg, float* __restrict__ mtxt)
{
    int wv = threadIdx.x >> 6, lane = threadIdx.x & 63;
    int r = blockIdx.x * 4 + wv;                 // 0..18431
    const float* W = blockIdx.y ? Wtxt : Wimg;
    const float* b = blockIdx.y ? btxt : bimg;
    float* out = blockIdx.y ? mtxt : mimg;
    const float* row = W + (long)r * DIMC;
    float acc = 0.f;
    #pragma unroll
    for (int j = 0; j < 12; j++) {
        float4v wvv = ((const float4v*)row)[lane + j * 64];
        float4v xv  = ((const float4v*)st)[lane + j * 64];
        acc += wvv[0] * xv[0] + wvv[1] * xv[1] + wvv[2] * xv[2] + wvv[3] * xv[3];
    }
    #pragma unroll
    for (int o = 32; o; o >>= 1) acc += __shfl_xor(acc, o);
    if (lane == 0) {
        int d = r / 6, j6 = r % 6;
        out[j6 * DIMC + d] = acc + b[r];
    }
}

// ---------------------------------------------------------------------------
__global__ __launch_bounds__(256)
void ln_mod(const float* __restrict__ x, const float* __restrict__ shift,
            const float* __restrict__ scale, unsigned short* __restrict__ out)
{
    __shared__ float red[8];
    long row = blockIdx.x;
    const float* xr = x + row * DIMC;
    float4v v[3];
    float sum = 0.f, sq = 0.f;
    #pragma unroll
    for (int j = 0; j < 3; j++) {
        v[j] = ((const float4v*)xr)[threadIdx.x + j * 256];
        #pragma unroll
        for (int c = 0; c < 4; c++) { sum += v[j][c]; sq += v[j][c] * v[j][c]; }
    }
    int lane = threadIdx.x & 63, wv = threadIdx.x >> 6;
    #pragma unroll
    for (int o = 32; o; o >>= 1) { sum += __shfl_xor(sum, o); sq += __shfl_xor(sq, o); }
    if (lane == 0) { red[wv] = sum; red[4 + wv] = sq; }
    __syncthreads();
    sum = red[0] + red[1] + red[2] + red[3];
    sq  = red[4] + red[5] + red[6] + red[7];
    float mu = sum / DIMC;
    float var = sq / DIMC - mu * mu;
    float rstd = rsqrtf(var + EPSF);
    #pragma unroll
    for (int j = 0; j < 3; j++) {
        int nb = (threadIdx.x + j * 256) * 4;
        #pragma unroll
        for (int c = 0; c < 4; c++) {
            int n = nb + c;
            float y = (v[j][c] - mu) * rstd * (scale[n] + 1.0f) + shift[n];
            out[row * DIMC + n] = f2bf(y);
        }
    }
}

// ---------------------------------------------------------------------------
__global__ __launch_bounds__(64)
void qkv_post(const float* __restrict__ qkv_img, const float* __restrict__ qkv_txt,
              const float* __restrict__ nqg, const float* __restrict__ nkg,
              const float* __restrict__ naqg, const float* __restrict__ nakg,
              const float* __restrict__ rc, const float* __restrict__ rs,
              unsigned short* __restrict__ q, unsigned short* __restrict__ k,
              unsigned short* __restrict__ vt)
{
    int s = blockIdx.x;   // 0..1279 (txt first)
    int h = blockIdx.y;
    int d0 = threadIdx.x; // 0..63
    const float *src, *gq, *gk;
    if (s < S_TXT) { src = qkv_txt + (long)s * 3 * DIMC; gq = naqg; gk = nakg; }
    else           { src = qkv_img + (long)(s - S_TXT) * 3 * DIMC; gq = nqg; gk = nkg; }

    float q0 = src[h * HD + d0],            q1 = src[h * HD + d0 + 64];
    float k0 = src[DIMC + h * HD + d0],     k1 = src[DIMC + h * HD + d0 + 64];
    float v0 = src[2 * DIMC + h * HD + d0], v1 = src[2 * DIMC + h * HD + d0 + 64];

    float sqq = q0 * q0 + q1 * q1;
    float sqk = k0 * k0 + k1 * k1;
    #pragma unroll
    for (int o = 32; o; o >>= 1) { sqq += __shfl_xor(sqq, o); sqk += __shfl_xor(sqk, o); }
    float rq = rsqrtf(sqq / (float)HD + EPSF);
    float rk = rsqrtf(sqk / (float)HD + EPSF);
    q0 *= rq * gq[d0]; q1 *= rq * gq[d0 + 64];
    k0 *= rk * gk[d0]; k1 *= rk * gk[d0 + 64];

    float qp0 = __shfl_xor(q0, 1), qp1 = __shfl_xor(q1, 1);
    float kp0 = __shfl_xor(k0, 1), kp1 = __shfl_xor(k1, 1);
    float c0 = rc[(long)s * HD + d0], c1 = rc[(long)s * HD + d0 + 64];
    float s0 = rs[(long)s * HD + d0], s1 = rs[(long)s * HD + d0 + 64];
    float sgn = (d0 & 1) ? 1.0f : -1.0f;
    float qo0 = q0 * c0 + sgn * qp0 * s0;
    float qo1 = q1 * c1 + sgn * qp1 * s1;
    float ko0 = k0 * c0 + sgn * kp0 * s0;
    float ko1 = k1 * c1 + sgn * kp1 * s1;

    const float scl = 0.08838834764831845f;   // 1/sqrt(128)
    long qkbase = ((long)h * S_TOT + s) * HD;
    q[qkbase + d0]      = f2bf(qo0 * scl);
    q[qkbase + d0 + 64] = f2bf(qo1 * scl);
    k[qkbase + d0]      = f2bf(ko0);
    k[qkbase + d0 + 64] = f2bf(ko1);
    vt[((long)h * HD + d0) * S_TOT + s]        = f2bf(v0);
    vt[((long)h * HD + d0 + 64) * S_TOT + s]   = f2bf(v1);
}

// ---------------------------------------------------------------------------
__global__ __launch_bounds__(256)
void softmax_k(unsigned short* __restrict__ scores)
{
    long row = (long)blockIdx.x * 4 + (threadIdx.x >> 6);
    int lane = threadIdx.x & 63;
    unsigned short* p = scores + row * S_TOT;
    float v[20];
    float mx = -1e30f;
    #pragma unroll
    for (int j = 0; j < 20; j++) { v[j] = b2f(p[lane + j * 64]); mx = fmaxf(mx, v[j]); }
    #pragma unroll
    for (int o = 32; o; o >>= 1) mx = fmaxf(mx, __shfl_xor(mx, o));
    float sum = 0.f;
    #pragma unroll
    for (int j = 0; j < 20; j++) { v[j] = expf(v[j] - mx); sum += v[j]; }
    #pragma unroll
    for (int o = 32; o; o >>= 1) sum += __shfl_xor(sum, o);
    float inv = 1.0f / sum;
    #pragma unroll
    for (int j = 0; j < 20; j++) p[lane + j * 64] = f2bf(v[j] * inv);
}

// ---------------------------------------------------------------------------
extern "C" void kernel_launch(void* const* d_in, const int* in_sizes, int n_in,
                              void* d_out, int out_size, void* d_ws, size_t ws_size,
                              hipStream_t stream)
{
    const float* hidden   = (const float*)d_in[0];
    const float* enc      = (const float*)d_in[1];
    const float* temb     = (const float*)d_in[2];
    const float* rope_cos = (const float*)d_in[3];
    const float* rope_sin = (const float*)d_in[4];
    const float* img_mod_w = (const float*)d_in[5];
    const float* img_mod_b = (const float*)d_in[6];
    const float* txt_mod_w = (const float*)d_in[7];
    const float* txt_mod_b = (const float*)d_in[8];
    const float* qkv_w     = (const float*)d_in[9];
    const float* qkv_b     = (const float*)d_in[10];
    const float* add_qkv_w = (const float*)d_in[11];
    const float* add_qkv_b = (const float*)d_in[12];
    const float* norm_q_g  = (const float*)d_in[13];
    const float* norm_k_g  = (const float*)d_in[14];
    const float* norm_aq_g = (const float*)d_in[15];
    const float* norm_ak_g = (const float*)d_in[16];
    const float* to_out_w  = (const float*)d_in[17];
    const float* to_out_b  = (const float*)d_in[18];
    const float* to_add_out_w = (const float*)d_in[19];
    const float* to_add_out_b = (const float*)d_in[20];
    const float* img_mlp_w1 = (const float*)d_in[21];
    const float* img_mlp_b1 = (const float*)d_in[22];
    const float* img_mlp_w2 = (const float*)d_in[23];
    const float* img_mlp_b2 = (const float*)d_in[24];
    const float* txt_mlp_w1 = (const float*)d_in[25];
    const float* txt_mlp_b1 = (const float*)d_in[26];
    const float* txt_mlp_w2 = (const float*)d_in[27];
    const float* txt_mlp_b2 = (const float*)d_in[28];

    char* w = (char*)d_ws;
    auto alloc = [&](size_t bytes) { char* p = w; w += (bytes + 255) & ~(size_t)255; return p; };
    float* silu_t  = (float*)alloc(DIMC * 4);
    float* mod_img = (float*)alloc(6 * DIMC * 4);
    float* mod_txt = (float*)alloc(6 * DIMC * 4);
    unsigned short* mA_img = (unsigned short*)alloc((long)S_IMG * DIMC * 2);
    unsigned short* mA_txt = (unsigned short*)alloc((long)S_TXT * DIMC * 2);
    float* qkv_img = (float*)alloc((long)S_IMG * 3 * DIMC * 4);
    float* qkv_txt = (float*)alloc((long)S_TXT * 3 * DIMC * 4);
    unsigned short* qb = (unsigned short*)alloc((long)HEADS * S_TOT * HD * 2);
    unsigned short* kb = (unsigned short*)alloc((long)HEADS * S_TOT * HD * 2);
    unsigned short* vt = (unsigned short*)alloc((long)HEADS * HD * S_TOT * 2);
    unsigned short* scores = (unsigned short*)alloc((long)HEADS * S_TOT * S_TOT * 2);
    unsigned short* attn = (unsigned short*)alloc((long)S_TOT * DIMC * 2);
    float* h1_img = (float*)alloc((long)S_IMG * DIMC * 4);
    float* h1_txt = (float*)alloc((long)S_TXT * DIMC * 4);
    unsigned short* gelu_img = (unsigned short*)alloc((long)S_IMG * FF * 2);
    unsigned short* gelu_txt = (unsigned short*)alloc((long)S_TXT * FF * 2);

    float* out_enc = (float*)d_out;
    float* out_hid = (float*)d_out + (long)S_TXT * DIMC;

    // 1. silu(temb), mod GEMVs
    silu_k<<<12, 256, 0, stream>>>(temb, silu_t);
    mod_gemv<<<dim3(4608, 2), 256, 0, stream>>>(silu_t, img_mod_w, img_mod_b,
                                                txt_mod_w, txt_mod_b, mod_img, mod_txt);

    // 2. LN1 + modulate -> bf16
    ln_mod<<<S_IMG, 256, 0, stream>>>(hidden, mod_img, mod_img + DIMC, mA_img);
    ln_mod<<<S_TXT, 256, 0, stream>>>(enc, mod_txt, mod_txt + DIMC, mA_txt);

    // 3. QKV GEMMs merged (img y=0..7, txt y=8..9)
    {
        GemmArgs gi{mA_img, qkv_w, qkv_b, qkv_img, nullptr, nullptr};
        GemmArgs gt{mA_txt, add_qkv_w, add_qkv_b, qkv_txt, nullptr, nullptr};
        gemm_bt<0, false><<<dim3(72, 10, 1), 256, 0, stream>>>(
            gi, gt, 8, DIMC, DIMC, DIMC, 3 * DIMC, 0, 0, 0);
    }

    // 4. RMS + RoPE + layout
    qkv_post<<<dim3(S_TOT, HEADS), 64, 0, stream>>>(
        qkv_img, qkv_txt, norm_q_g, norm_k_g, norm_aq_g, norm_ak_g,
        rope_cos, rope_sin, qb, kb, vt);

    // 5. scores = q k^T (scale folded in q), softmax, attn = P v
    {
        GemmArgs gs{qb, kb, nullptr, scores, nullptr, nullptr};
        gemm_bt<1, true><<<dim3(10, 10, HEADS), 256, 0, stream>>>(
            gs, gs, 10, HD, HD, HD, S_TOT,
            (long)S_TOT * HD, (long)S_TOT * HD, (long)S_TOT * S_TOT);
    }
    softmax_k<<<(HEADS * S_TOT) / 4, 256, 0, stream>>>(scores);
    {
        GemmArgs gp{scores, vt, nullptr, attn, nullptr, nullptr};
        gemm_bt<1, true><<<dim3(1, 10, HEADS), 256, 0, stream>>>(
            gp, gp, 10, S_TOT, S_TOT, S_TOT, DIMC,
            (long)S_TOT * S_TOT, (long)HD * S_TOT, HD);
    }

    // 6. output projections + gated residual (merged img/txt)
    {
        GemmArgs gi{attn + (long)S_TXT * DIMC, to_out_w, to_out_b, h1_img, hidden, mod_img + 2 * DIMC};
        GemmArgs gt{attn, to_add_out_w, to_add_out_b, h1_txt, enc, mod_txt + 2 * DIMC};
        gemm_bt<3, false><<<dim3(24, 10, 1), 256, 0, stream>>>(
            gi, gt, 8, DIMC, DIMC, DIMC, DIMC, 0, 0, 0);
    }

    // 7. LN2 + modulate
    ln_mod<<<S_IMG, 256, 0, stream>>>(h1_img, mod_img + 3 * DIMC, mod_img + 4 * DIMC, mA_img);
    ln_mod<<<S_TXT, 256, 0, stream>>>(h1_txt, mod_txt + 3 * DIMC, mod_txt + 4 * DIMC, mA_txt);

    // 8. MLP w1 + gelu (merged), then w2 + gated residual -> d_out (merged)
    {
        GemmArgs gi{mA_img, img_mlp_w1, img_mlp_b1, gelu_img, nullptr, nullptr};
        GemmArgs gt{mA_txt, txt_mlp_w1, txt_mlp_b1, gelu_txt, nullptr, nullptr};
        gemm_bt<2, false><<<dim3(96, 10, 1), 256, 0, stream>>>(
            gi, gt, 8, DIMC, DIMC, DIMC, FF, 0, 0, 0);
    }
    {
        GemmArgs gi{gelu_img, img_mlp_w2, img_mlp_b2, out_hid, h1_img, mod_img + 5 * DIMC};
        GemmArgs gt{gelu_txt, txt_mlp_w2, txt_mlp_b2, out_enc, h1_txt, mod_txt + 5 * DIMC};
        gemm_bt<3, false><<<dim3(24, 10, 1), 256, 0, stream>>>(
            gi, gt, 8, FF, FF, FF, DIMC, 0, 0, 0);
    }
}